// Round 1
// 4347.345 us; speedup vs baseline: 1.7692x; 1.7692x over previous
//
#include <hip/hip_runtime.h>
#include <math.h>

// ---------------------------------------------------------------------------
// Spiking transformer block — fp64-exact up to every spike decision.
//  * All GEMMs now run on the fp64 matrix pipe (v_mfma_f64_16x16x4_f64):
//    MfmaUtil was 0, VALU was the 40%-of-peak bottleneck.
//  * 4 waves/block in 2x2; wave tile 32x32 (WT=2) or 16x16 (WT=1 for the
//    narrow wk/wv GEMMs so the grid fills all 256 CUs).
//  * Register prefetch of next K-slab issued before the MFMA phase so HBM
//    latency hides under ~1-2k cycles of matrix work (T14 pattern).
//  * Numerics: fp64 accumulate, identical transforms -> spike decisions
//    unchanged vs previous passing kernel (only summation order differs).
// ---------------------------------------------------------------------------

typedef double f64x4 __attribute__((ext_vector_type(4)));

__device__ __forceinline__ unsigned spike_pat_d(double y) {
    double v = 0.0; unsigned p = 0u;
#pragma unroll
    for (int t = 0; t < 10; ++t) {
        v += y;
        bool s = (v >= 1.0);
        p |= s ? (1u << t) : 0u;
        v = s ? 0.0 : v;
    }
    return p;
}

__device__ __forceinline__ int spike_count_d(double y) {
    double v = 0.0; int c = 0;
#pragma unroll
    for (int t = 0; t < 10; ++t) {
        v += y;
        bool s = (v >= 1.0);
        c += s ? 1 : 0;
        v = s ? 0.0 : v;
    }
    return c;
}

// ----------------------------- RMSNorm (f32 in -> f64 out) -----------------
__global__ __launch_bounds__(256) void rms_f_kernel(const float* __restrict__ x,
                                                    const float* __restrict__ w,
                                                    double* __restrict__ out)
{
    const int row = blockIdx.x, tid = threadIdx.x;
    const float4* xr = (const float4*)(x + (size_t)row * 4096);
    const float4* wr = (const float4*)w;
    double* orow = out + (size_t)row * 4096;
    float4 v[4];
    double ss = 0.0;
#pragma unroll
    for (int i = 0; i < 4; ++i) {
        v[i] = xr[tid + (i << 8)];
        ss += (double)v[i].x * v[i].x + (double)v[i].y * v[i].y +
              (double)v[i].z * v[i].z + (double)v[i].w * v[i].w;
    }
#pragma unroll
    for (int off = 32; off > 0; off >>= 1) ss += __shfl_down(ss, off, 64);
    __shared__ double red[4];
    if ((tid & 63) == 0) red[tid >> 6] = ss;
    __syncthreads();
    double m = (red[0] + red[1] + red[2] + red[3]) * (1.0 / 4096.0);
    double sc = 1.0 / sqrt(m + 1e-5);
#pragma unroll
    for (int i = 0; i < 4; ++i) {
        float4 wv = wr[tid + (i << 8)];
        int b = (tid + (i << 8)) << 2;
        orow[b + 0] = ((double)v[i].x * sc) * (double)wv.x;
        orow[b + 1] = ((double)v[i].y * sc) * (double)wv.y;
        orow[b + 2] = ((double)v[i].z * sc) * (double)wv.z;
        orow[b + 3] = ((double)v[i].w * sc) * (double)wv.w;
    }
}

// ----------------------------- RMSNorm (f64 in -> f64 out) -----------------
__global__ __launch_bounds__(256) void rms_d_kernel(const double* __restrict__ x,
                                                    const float* __restrict__ w,
                                                    double* __restrict__ out)
{
    const int row = blockIdx.x, tid = threadIdx.x;
    const double2* xr = (const double2*)(x + (size_t)row * 4096);
    const float2* wr = (const float2*)w;
    double* orow = out + (size_t)row * 4096;
    double2 v[8];
    double ss = 0.0;
#pragma unroll
    for (int i = 0; i < 8; ++i) {
        v[i] = xr[tid + (i << 8)];
        ss += v[i].x * v[i].x + v[i].y * v[i].y;
    }
#pragma unroll
    for (int off = 32; off > 0; off >>= 1) ss += __shfl_down(ss, off, 64);
    __shared__ double red[4];
    if ((tid & 63) == 0) red[tid >> 6] = ss;
    __syncthreads();
    double m = (red[0] + red[1] + red[2] + red[3]) * (1.0 / 4096.0);
    double sc = 1.0 / sqrt(m + 1e-5);
#pragma unroll
    for (int i = 0; i < 8; ++i) {
        float2 wv = wr[tid + (i << 8)];
        int b = (tid + (i << 8)) << 1;
        orow[b + 0] = (v[i].x * sc) * (double)wv.x;
        orow[b + 1] = (v[i].y * sc) * (double)wv.y;
    }
}

// ----------------------------- MFMA GEMM ------------------------------------
// C[m,n] = sum_k A[m,k]*W[n,k]  (NT, K-contiguous). fp64 MFMA accumulate.
// MODE 0: A f64, dual relu -> pattern u32 (pos lo16 | neg hi16)   (QKV)
// MODE 1: A f64, dual relu -> s3 int8  = cnt(yp)-cnt(yn)           (w3)
// MODE 2: A f64, pos relu  -> s1 uint8 = cnt(yp)                   (w1)
// MODE 3: A f64 plain, ADD f32 -> C f64 = ADD + acc                (wo)
// MODE 4: A = (s1/10)*(s3/10) from u8/i8, ADD f64 -> C f32         (w2)
// WT: per-wave 16x16 fragment repeat (2 -> 64x64 block tile, 1 -> 32x32).
template <int MODE, int WT>
__global__ __launch_bounds__(256, 2) void gemm_kernel(
    const void* __restrict__ Av, const void* __restrict__ A2v,
    const float* __restrict__ W, const void* __restrict__ ADDv,
    void* __restrict__ C0v, int K, int N)
{
    constexpr bool DUAL = (MODE == 0 || MODE == 1);
    constexpr int NB = DUAL ? 2 : 1;
    constexpr int BMN = 32 * WT;          // block tile edge
    constexpr int EPT = 2 * WT;           // staged elements per thread (per k-step)
    __shared__ __align__(16) double As[NB][16][BMN + 4];
    __shared__ __align__(16) float  Ws[16][BMN + 8];

    const int tid = threadIdx.x;
    const int m0 = blockIdx.y * BMN, n0 = blockIdx.x * BMN;

    // staging coords: EPT consecutive k per thread
    const int lrow = tid / (16 / EPT);            // 0..BMN-1
    const int lk   = (tid % (16 / EPT)) * EPT;    // k within 16-slab

    // wave/fragment coords
    const int l  = tid & 63;
    const int wid = tid >> 6;
    const int wm = wid >> 1, wn = wid & 1;        // 2x2 wave grid
    const int lr = l & 15;                        // row (A) / col (B,D)
    const int kf = l >> 4;                        // k within 4-slab

    f64x4 accp[WT][WT] = {};
    f64x4 accn[WT][WT] = {};

    const float* Wpt = W + (size_t)(n0 + lrow) * K + lk;
    const double* Apt = nullptr;
    const unsigned char* S1t = nullptr;
    const signed char* S3t = nullptr;
    if constexpr (MODE <= 3) {
        Apt = (const double*)Av + (size_t)(m0 + lrow) * K + lk;
    } else {
        S1t = (const unsigned char*)Av + (size_t)(m0 + lrow) * K + lk;
        S3t = (const signed char*)A2v + (size_t)(m0 + lrow) * K + lk;
    }

    auto LOAD = [&](int k0, double* a, float* w) {
        if constexpr (MODE == 4) {
            uchar4 c1 = *(const uchar4*)(S1t + k0);
            char4  c3 = *(const char4*)(S3t + k0);
            a[0] = ((double)c1.x * 0.1) * ((double)c3.x * 0.1);
            a[1] = ((double)c1.y * 0.1) * ((double)c3.y * 0.1);
            a[2] = ((double)c1.z * 0.1) * ((double)c3.z * 0.1);
            a[3] = ((double)c1.w * 0.1) * ((double)c3.w * 0.1);
        } else if constexpr (EPT == 4) {
            double2 a01 = *(const double2*)(Apt + k0);
            double2 a23 = *(const double2*)(Apt + k0 + 2);
            a[0] = a01.x; a[1] = a01.y; a[2] = a23.x; a[3] = a23.y;
        } else {
            double2 a01 = *(const double2*)(Apt + k0);
            a[0] = a01.x; a[1] = a01.y;
        }
        if constexpr (EPT == 4) {
            float4 wv = *(const float4*)(Wpt + k0);
            w[0] = wv.x; w[1] = wv.y; w[2] = wv.z; w[3] = wv.w;
        } else {
            float2 wv = *(const float2*)(Wpt + k0);
            w[0] = wv.x; w[1] = wv.y;
        }
    };

    double a_cur[EPT]; float w_cur[EPT];
    LOAD(0, a_cur, w_cur);

    for (int k0 = 0; k0 < K; k0 += 16) {
        // ---- stage current slab into LDS (mode transform at write) ----
#pragma unroll
        for (int j = 0; j < EPT; ++j) {
            if constexpr (DUAL) {
                As[0][lk + j][lrow] = fmax(a_cur[j], 0.0);
                As[1][lk + j][lrow] = fmax(-a_cur[j], 0.0);
            } else if constexpr (MODE == 2) {
                As[0][lk + j][lrow] = fmax(a_cur[j], 0.0);
            } else {
                As[0][lk + j][lrow] = a_cur[j];
            }
            Ws[lk + j][lrow] = w_cur[j];
        }
        __syncthreads();

        // ---- issue next slab's global loads (hide under MFMA phase) ----
        double a_nxt[EPT]; float w_nxt[EPT];
        if (k0 + 16 < K) LOAD(k0 + 16, a_nxt, w_nxt);

        // ---- MFMA phase: 4 k-slabs of 4 ----
#pragma unroll
        for (int ks = 0; ks < 4; ++ks) {
            const int kk = (ks << 2) + kf;
            double b[WT], p[WT];
#pragma unroll
            for (int nt = 0; nt < WT; ++nt)
                b[nt] = (double)Ws[kk][wn * (16 * WT) + nt * 16 + lr];
#pragma unroll
            for (int mt = 0; mt < WT; ++mt)
                p[mt] = As[0][kk][wm * (16 * WT) + mt * 16 + lr];
#pragma unroll
            for (int mt = 0; mt < WT; ++mt)
#pragma unroll
                for (int nt = 0; nt < WT; ++nt)
                    accp[mt][nt] = __builtin_amdgcn_mfma_f64_16x16x4f64(
                        p[mt], b[nt], accp[mt][nt], 0, 0, 0);
            if constexpr (DUAL) {
                double q[WT];
#pragma unroll
                for (int mt = 0; mt < WT; ++mt)
                    q[mt] = As[1][kk][wm * (16 * WT) + mt * 16 + lr];
#pragma unroll
                for (int mt = 0; mt < WT; ++mt)
#pragma unroll
                    for (int nt = 0; nt < WT; ++nt)
                        accn[mt][nt] = __builtin_amdgcn_mfma_f64_16x16x4f64(
                            q[mt], b[nt], accn[mt][nt], 0, 0, 0);
            }
        }
        __syncthreads();

#pragma unroll
        for (int j = 0; j < EPT; ++j) a_cur[j] = a_nxt[j];
#pragma unroll
        for (int j = 0; j < EPT; ++j) w_cur[j] = w_nxt[j];
    }

    // ---- epilogue: D lane layout col=lane&15, row=4*(lane>>4)+r ----
#pragma unroll
    for (int mt = 0; mt < WT; ++mt) {
#pragma unroll
        for (int nt = 0; nt < WT; ++nt) {
#pragma unroll
            for (int r = 0; r < 4; ++r) {
                const int m = m0 + wm * (16 * WT) + mt * 16 + (kf << 2) + r;
                const int n = n0 + wn * (16 * WT) + nt * 16 + lr;
                const size_t idx = (size_t)m * N + n;
                const double vp = accp[mt][nt][r];
                if constexpr (MODE == 0) {
                    const double vn = accn[mt][nt][r];
                    ((unsigned*)C0v)[idx] =
                        spike_pat_d(vp) | (spike_pat_d(vn) << 16);
                } else if constexpr (MODE == 1) {
                    const double vn = accn[mt][nt][r];
                    ((signed char*)C0v)[idx] =
                        (signed char)(spike_count_d(vp) - spike_count_d(vn));
                } else if constexpr (MODE == 2) {
                    ((unsigned char*)C0v)[idx] =
                        (unsigned char)spike_count_d(vp);
                } else if constexpr (MODE == 3) {
                    ((double*)C0v)[idx] =
                        (double)((const float*)ADDv)[idx] + vp;
                } else {
                    ((float*)C0v)[idx] =
                        (float)(((const double*)ADDv)[idx] + vp);
                }
            }
        }
    }
}

// ----------------------------- Attention core ------------------------------
// One block per token. Patterns pre-packed (pos lo16 | neg hi16).
// S8[t][h][j8] integer-exact; xa = 0.5*S8.V8 (exact in fp32); out f64 /10.
__global__ __launch_bounds__(256) void attn_kernel(
    const unsigned* __restrict__ patq_g, const unsigned* __restrict__ patk_g,
    const unsigned* __restrict__ patv_g, double* __restrict__ Aout)
{
    __shared__ __align__(16) unsigned patq[4096];
    __shared__ __align__(16) unsigned patk[1024];
    __shared__ __align__(16) unsigned patv[1024];
    __shared__ int S8[10][32][8];
    const int n = blockIdx.x, tid = threadIdx.x;

    const uint4* q4 = (const uint4*)(patq_g + (size_t)n * 4096);
#pragma unroll
    for (int r = 0; r < 4; ++r)
        ((uint4*)patq)[tid + (r << 8)] = q4[tid + (r << 8)];
    ((uint4*)patk)[tid] = ((const uint4*)(patk_g + (size_t)n * 1024))[tid];
    ((uint4*)patv)[tid] = ((const uint4*)(patv_g + (size_t)n * 1024))[tid];
    __syncthreads();

    const int hi = tid >> 3;  // head 0..31
    const int j8 = tid & 7;   // kv-head (phase 1) / d-group (phase 2)

    int sacc[10] = {0, 0, 0, 0, 0, 0, 0, 0, 0, 0};
    for (int d = 0; d < 128; ++d) {
        unsigned q = patq[(hi << 7) + d];
        unsigned k = patk[(j8 << 7) + d];
        unsigned qp = q & 0xFFFFu, qn = q >> 16;
        unsigned kp = k & 0xFFFFu, kn = k >> 16;
        unsigned pos = (qp & kp) | (qn & kn);
        unsigned neg = (qp & kn) | (qn & kp);
#pragma unroll
        for (int t = 0; t < 10; ++t)
            sacc[t] += (int)((pos >> t) & 1u) - (int)((neg >> t) & 1u);
    }
#pragma unroll
    for (int t = 0; t < 10; ++t) S8[t][hi][j8] = sacc[t];
    __syncthreads();

    float xacc[16];
#pragma unroll
    for (int dd = 0; dd < 16; ++dd) xacc[dd] = 0.f;

    for (int t = 0; t < 10; ++t) {
        int s8r[8];
#pragma unroll
        for (int jj = 0; jj < 8; ++jj) s8r[jj] = S8[t][hi][jj];
#pragma unroll
        for (int dd = 0; dd < 16; ++dd) {
            int d = (j8 << 4) + dd;
            int acc = 0;
#pragma unroll
            for (int jj = 0; jj < 8; ++jj) {
                unsigned v = patv[(jj << 7) + d];
                int vv = (int)((v >> t) & 1u) - (int)((v >> (t + 16)) & 1u);
                acc += s8r[jj] * vv;
            }
            xacc[dd] += 0.5f * (float)acc;
        }
    }
#pragma unroll
    for (int dd = 0; dd < 16; ++dd) {
        int d = (j8 << 4) + dd;
        Aout[(size_t)n * 4096 + (d << 5) + hi] = (double)xacc[dd] / 10.0;
    }
}

// ----------------------------- Launch --------------------------------------
extern "C" void kernel_launch(void* const* d_in, const int* in_sizes, int n_in,
                              void* d_out, int out_size, void* d_ws, size_t ws_size,
                              hipStream_t stream)
{
    const float* x   = (const float*)d_in[0];
    const float* anw = (const float*)d_in[2];
    const float* fnw = (const float*)d_in[3];
    const float* wq  = (const float*)d_in[4];
    const float* wk  = (const float*)d_in[5];
    const float* wv  = (const float*)d_in[6];
    const float* wo  = (const float*)d_in[7];
    const float* w1  = (const float*)d_in[8];
    const float* w2  = (const float*)d_in[9];
    const float* w3  = (const float*)d_in[10];
    float* out = (float*)d_out;

    double* h1 = (double*)d_ws;            // 256x4096 f64
    double* Ap = h1 + 1048576;             // 256x4096 f64 (pooled attn, c=d*32+h)
    double* hb = Ap + 1048576;             // 256x4096 f64 residual h
    double* h2 = hb + 1048576;             // 256x4096 f64
    unsigned* patq = (unsigned*)(h2 + 1048576);  // 256x4096 u32
    unsigned* patk = patq + 1048576;             // 256x1024 u32
    unsigned* patv = patk + 262144;              // 256x1024 u32
    unsigned char* s1 = (unsigned char*)(patv + 262144);  // 256x14336 u8
    signed char*  s3 = (signed char*)(s1 + 3670016);      // 256x14336 i8
    // total ~45 MB of d_ws

    dim3 blk(256);
    rms_f_kernel<<<dim3(256), blk, 0, stream>>>(x, anw, h1);
    gemm_kernel<0, 2><<<dim3(64, 4), blk, 0, stream>>>(h1, nullptr, wq, nullptr, patq, 4096, 4096);
    gemm_kernel<0, 1><<<dim3(32, 8), blk, 0, stream>>>(h1, nullptr, wk, nullptr, patk, 4096, 1024);
    gemm_kernel<0, 1><<<dim3(32, 8), blk, 0, stream>>>(h1, nullptr, wv, nullptr, patv, 4096, 1024);
    attn_kernel<<<dim3(256), blk, 0, stream>>>(patq, patk, patv, Ap);
    gemm_kernel<3, 2><<<dim3(64, 4), blk, 0, stream>>>(Ap, nullptr, wo, x, hb, 4096, 4096);
    rms_d_kernel<<<dim3(256), blk, 0, stream>>>(hb, fnw, h2);
    gemm_kernel<1, 2><<<dim3(224, 4), blk, 0, stream>>>(h2, nullptr, w3, nullptr, s3, 4096, 14336);
    gemm_kernel<2, 2><<<dim3(224, 4), blk, 0, stream>>>(h2, nullptr, w1, nullptr, s1, 4096, 14336);
    gemm_kernel<4, 2><<<dim3(64, 4), blk, 0, stream>>>(s1, s3, w2, hb, out, 14336, 4096);
}

// Round 2
// 3910.103 us; speedup vs baseline: 1.9670x; 1.1118x over previous
//
#include <hip/hip_runtime.h>
#include <math.h>

// ---------------------------------------------------------------------------
// Spiking transformer block — fp64-exact up to every spike decision.
//  * All GEMMs on the fp64 matrix pipe (v_mfma_f64_16x16x4_f64).
//  * Dual-relu trick: relu(-a) = relu(a) - a  =>  store only RAW a in LDS,
//    keep two accumulators (accA = sum relu(a)w, accR = sum a*w); neg acc is
//    accA - accR at epilogue. Halves LDS (13.3 KB/buffer) and LDS traffic.
//  * Double-buffered LDS, ONE __syncthreads per 16-K slab; global prefetch
//    issued before the MFMA phase (T14), LDS write after it.
//  * 26.6 KB LDS -> 6 blocks/CU resident: barrier stalls hidden by other
//    blocks' MFMA waves.
//  * Fused dispatches: {wq,wk,wv} in one 384-block launch; {w3,w1} in one
//    1792-block launch.
// ---------------------------------------------------------------------------

typedef double f64x4 __attribute__((ext_vector_type(4)));

__device__ __forceinline__ unsigned spike_pat_d(double y) {
    double v = 0.0; unsigned p = 0u;
#pragma unroll
    for (int t = 0; t < 10; ++t) {
        v += y;
        bool s = (v >= 1.0);
        p |= s ? (1u << t) : 0u;
        v = s ? 0.0 : v;
    }
    return p;
}

__device__ __forceinline__ int spike_count_d(double y) {
    double v = 0.0; int c = 0;
#pragma unroll
    for (int t = 0; t < 10; ++t) {
        v += y;
        bool s = (v >= 1.0);
        c += s ? 1 : 0;
        v = s ? 0.0 : v;
    }
    return c;
}

// ----------------------------- RMSNorm (f32 in -> f64 out) -----------------
__global__ __launch_bounds__(256) void rms_f_kernel(const float* __restrict__ x,
                                                    const float* __restrict__ w,
                                                    double* __restrict__ out)
{
    const int row = blockIdx.x, tid = threadIdx.x;
    const float4* xr = (const float4*)(x + (size_t)row * 4096);
    const float4* wr = (const float4*)w;
    double* orow = out + (size_t)row * 4096;
    float4 v[4];
    double ss = 0.0;
#pragma unroll
    for (int i = 0; i < 4; ++i) {
        v[i] = xr[tid + (i << 8)];
        ss += (double)v[i].x * v[i].x + (double)v[i].y * v[i].y +
              (double)v[i].z * v[i].z + (double)v[i].w * v[i].w;
    }
#pragma unroll
    for (int off = 32; off > 0; off >>= 1) ss += __shfl_down(ss, off, 64);
    __shared__ double red[4];
    if ((tid & 63) == 0) red[tid >> 6] = ss;
    __syncthreads();
    double m = (red[0] + red[1] + red[2] + red[3]) * (1.0 / 4096.0);
    double sc = 1.0 / sqrt(m + 1e-5);
#pragma unroll
    for (int i = 0; i < 4; ++i) {
        float4 wv = wr[tid + (i << 8)];
        int b = (tid + (i << 8)) << 2;
        orow[b + 0] = ((double)v[i].x * sc) * (double)wv.x;
        orow[b + 1] = ((double)v[i].y * sc) * (double)wv.y;
        orow[b + 2] = ((double)v[i].z * sc) * (double)wv.z;
        orow[b + 3] = ((double)v[i].w * sc) * (double)wv.w;
    }
}

// ----------------------------- RMSNorm (f64 in -> f64 out) -----------------
__global__ __launch_bounds__(256) void rms_d_kernel(const double* __restrict__ x,
                                                    const float* __restrict__ w,
                                                    double* __restrict__ out)
{
    const int row = blockIdx.x, tid = threadIdx.x;
    const double2* xr = (const double2*)(x + (size_t)row * 4096);
    const float2* wr = (const float2*)w;
    double* orow = out + (size_t)row * 4096;
    double2 v[8];
    double ss = 0.0;
#pragma unroll
    for (int i = 0; i < 8; ++i) {
        v[i] = xr[tid + (i << 8)];
        ss += v[i].x * v[i].x + v[i].y * v[i].y;
    }
#pragma unroll
    for (int off = 32; off > 0; off >>= 1) ss += __shfl_down(ss, off, 64);
    __shared__ double red[4];
    if ((tid & 63) == 0) red[tid >> 6] = ss;
    __syncthreads();
    double m = (red[0] + red[1] + red[2] + red[3]) * (1.0 / 4096.0);
    double sc = 1.0 / sqrt(m + 1e-5);
#pragma unroll
    for (int i = 0; i < 8; ++i) {
        float2 wv = wr[tid + (i << 8)];
        int b = (tid + (i << 8)) << 1;
        orow[b + 0] = (v[i].x * sc) * (double)wv.x;
        orow[b + 1] = (v[i].y * sc) * (double)wv.y;
    }
}

// ----------------------------- MFMA GEMM body -------------------------------
// C[m,n] = sum_k A[m,k]*W[n,k]  (NT, K-contiguous). fp64 MFMA accumulate.
// 64x64 block tile, 4 waves 2x2, each wave 32x32 (2x2 fragments).
// MODE 0: dual relu -> pattern u32 (pos lo16 | neg hi16)   (QKV)
// MODE 1: dual relu -> s3 int8  = cnt(yp)-cnt(yn)           (w3)
// MODE 2: pos relu  -> s1 uint8 = cnt(yp)                   (w1)
// MODE 3: plain, ADD f32 -> C f64 = ADD + acc               (wo)
// MODE 4: A = (s1/10)*(s3/10) from u8/i8, ADD f64 -> C f32  (w2)
template <int MODE>
__device__ __forceinline__ void gemm_body(
    const void* __restrict__ Av, const void* __restrict__ A2v,
    const float* __restrict__ W, const void* __restrict__ ADDv,
    void* __restrict__ C0v, int K, int N, int m0, int n0,
    double As[2][16][68], float Ws[2][16][72])
{
    constexpr bool DUAL = (MODE == 0 || MODE == 1);
    const int tid = threadIdx.x;

    // staging coords: 4 consecutive k per thread
    const int lrow = tid >> 2;          // 0..63
    const int lk   = (tid & 3) << 2;    // 0,4,8,12

    // wave/fragment coords
    const int l   = tid & 63;
    const int wid = tid >> 6;
    const int wm = wid >> 1, wn = wid & 1;   // 2x2 wave grid
    const int lr = l & 15;                   // row (A) / col (B,D)
    const int kf = l >> 4;                   // k within 4-slab

    f64x4 accA[2][2] = {};   // sum relu(a)*w (DUAL) or the only acc
    f64x4 accR[2][2] = {};   // sum a*w (DUAL only)

    const float* Wpt = W + (size_t)(n0 + lrow) * K + lk;
    const double* Apt = nullptr;
    const unsigned char* S1t = nullptr;
    const signed char* S3t = nullptr;
    if constexpr (MODE <= 3) {
        Apt = (const double*)Av + (size_t)(m0 + lrow) * K + lk;
    } else {
        S1t = (const unsigned char*)Av + (size_t)(m0 + lrow) * K + lk;
        S3t = (const signed char*)A2v + (size_t)(m0 + lrow) * K + lk;
    }

    auto LOAD = [&](int k0, double* a, float* w) {
        if constexpr (MODE == 4) {
            uchar4 c1 = *(const uchar4*)(S1t + k0);
            char4  c3 = *(const char4*)(S3t + k0);
            a[0] = ((double)c1.x * 0.1) * ((double)c3.x * 0.1);
            a[1] = ((double)c1.y * 0.1) * ((double)c3.y * 0.1);
            a[2] = ((double)c1.z * 0.1) * ((double)c3.z * 0.1);
            a[3] = ((double)c1.w * 0.1) * ((double)c3.w * 0.1);
        } else {
            double2 a01 = *(const double2*)(Apt + k0);
            double2 a23 = *(const double2*)(Apt + k0 + 2);
            a[0] = a01.x; a[1] = a01.y; a[2] = a23.x; a[3] = a23.y;
        }
        float4 wv = *(const float4*)(Wpt + k0);
        w[0] = wv.x; w[1] = wv.y; w[2] = wv.z; w[3] = wv.w;
    };

    auto STORE = [&](int buf, const double* a, const float* w) {
#pragma unroll
        for (int j = 0; j < 4; ++j) {
            if constexpr (MODE == 2)
                As[buf][lk + j][lrow] = fmax(a[j], 0.0);
            else
                As[buf][lk + j][lrow] = a[j];
            Ws[buf][lk + j][lrow] = w[j];
        }
    };

    double a_cur[4]; float w_cur[4];
    LOAD(0, a_cur, w_cur);
    STORE(0, a_cur, w_cur);
    __syncthreads();

    int p = 0;
    for (int k0 = 0; k0 < K; k0 += 16) {
        const bool last = (k0 + 16 >= K);
        double a_nxt[4]; float w_nxt[4];
        if (!last) LOAD(k0 + 16, a_nxt, w_nxt);   // HBM latency hides under MFMA

        // ---- MFMA phase on LDS[p]: 4 k-slabs of 4 ----
#pragma unroll
        for (int ks = 0; ks < 4; ++ks) {
            const int kk = (ks << 2) + kf;
            double b0 = (double)Ws[p][kk][wn * 32 + lr];
            double b1 = (double)Ws[p][kk][wn * 32 + 16 + lr];
            double r0 = As[p][kk][wm * 32 + lr];
            double r1 = As[p][kk][wm * 32 + 16 + lr];
            if constexpr (DUAL) {
                double q0 = fmax(r0, 0.0), q1 = fmax(r1, 0.0);
                accA[0][0] = __builtin_amdgcn_mfma_f64_16x16x4f64(q0, b0, accA[0][0], 0, 0, 0);
                accA[0][1] = __builtin_amdgcn_mfma_f64_16x16x4f64(q0, b1, accA[0][1], 0, 0, 0);
                accA[1][0] = __builtin_amdgcn_mfma_f64_16x16x4f64(q1, b0, accA[1][0], 0, 0, 0);
                accA[1][1] = __builtin_amdgcn_mfma_f64_16x16x4f64(q1, b1, accA[1][1], 0, 0, 0);
                accR[0][0] = __builtin_amdgcn_mfma_f64_16x16x4f64(r0, b0, accR[0][0], 0, 0, 0);
                accR[0][1] = __builtin_amdgcn_mfma_f64_16x16x4f64(r0, b1, accR[0][1], 0, 0, 0);
                accR[1][0] = __builtin_amdgcn_mfma_f64_16x16x4f64(r1, b0, accR[1][0], 0, 0, 0);
                accR[1][1] = __builtin_amdgcn_mfma_f64_16x16x4f64(r1, b1, accR[1][1], 0, 0, 0);
            } else {
                accA[0][0] = __builtin_amdgcn_mfma_f64_16x16x4f64(r0, b0, accA[0][0], 0, 0, 0);
                accA[0][1] = __builtin_amdgcn_mfma_f64_16x16x4f64(r0, b1, accA[0][1], 0, 0, 0);
                accA[1][0] = __builtin_amdgcn_mfma_f64_16x16x4f64(r1, b0, accA[1][0], 0, 0, 0);
                accA[1][1] = __builtin_amdgcn_mfma_f64_16x16x4f64(r1, b1, accA[1][1], 0, 0, 0);
            }
        }

        if (!last) {
            STORE(p ^ 1, a_nxt, w_nxt);   // waits vmcnt for a_nxt internally
            __syncthreads();              // one barrier per K-slab
            p ^= 1;
        }
    }

    // ---- epilogue: D lane layout col=lane&15, row=4*(lane>>4)+r ----
    // DUAL: pos = accA, neg = accA - accR  (relu(-a) = relu(a) - a, fp64)
#pragma unroll
    for (int mt = 0; mt < 2; ++mt) {
#pragma unroll
        for (int nt = 0; nt < 2; ++nt) {
#pragma unroll
            for (int r = 0; r < 4; ++r) {
                const int m = m0 + wm * 32 + mt * 16 + (kf << 2) + r;
                const int n = n0 + wn * 32 + nt * 16 + lr;
                const size_t idx = (size_t)m * N + n;
                const double vA = accA[mt][nt][r];
                if constexpr (MODE == 0) {
                    const double vN = vA - accR[mt][nt][r];
                    ((unsigned*)C0v)[idx] =
                        spike_pat_d(vA) | (spike_pat_d(vN) << 16);
                } else if constexpr (MODE == 1) {
                    const double vN = vA - accR[mt][nt][r];
                    ((signed char*)C0v)[idx] =
                        (signed char)(spike_count_d(vA) - spike_count_d(vN));
                } else if constexpr (MODE == 2) {
                    ((unsigned char*)C0v)[idx] =
                        (unsigned char)spike_count_d(vA);
                } else if constexpr (MODE == 3) {
                    ((double*)C0v)[idx] =
                        (double)((const float*)ADDv)[idx] + vA;
                } else {
                    ((float*)C0v)[idx] =
                        (float)(((const double*)ADDv)[idx] + vA);
                }
            }
        }
    }
}

// ----------------------------- GEMM kernels ---------------------------------
__global__ __launch_bounds__(256, 2) void gemm_qkv_kernel(
    const double* __restrict__ h1,
    const float* __restrict__ wq, const float* __restrict__ wk,
    const float* __restrict__ wv,
    unsigned* __restrict__ patq, unsigned* __restrict__ patk,
    unsigned* __restrict__ patv)
{
    __shared__ __align__(16) double As[2][16][68];
    __shared__ __align__(16) float  Ws[2][16][72];
    const int bx = blockIdx.x, m0 = blockIdx.y << 6;
    const float* W; unsigned* C; int N, n0;
    if (bx < 64)      { W = wq; C = patq; N = 4096; n0 = bx << 6; }
    else if (bx < 80) { W = wk; C = patk; N = 1024; n0 = (bx - 64) << 6; }
    else              { W = wv; C = patv; N = 1024; n0 = (bx - 80) << 6; }
    gemm_body<0>(h1, nullptr, W, nullptr, C, 4096, N, m0, n0, As, Ws);
}

__global__ __launch_bounds__(256, 2) void gemm_ffn13_kernel(
    const double* __restrict__ h2,
    const float* __restrict__ w3, const float* __restrict__ w1,
    signed char* __restrict__ s3, unsigned char* __restrict__ s1)
{
    __shared__ __align__(16) double As[2][16][68];
    __shared__ __align__(16) float  Ws[2][16][72];
    const int n0 = blockIdx.x << 6;
    if (blockIdx.y < 4)
        gemm_body<1>(h2, nullptr, w3, nullptr, s3, 4096, 14336,
                     blockIdx.y << 6, n0, As, Ws);
    else
        gemm_body<2>(h2, nullptr, w1, nullptr, s1, 4096, 14336,
                     (blockIdx.y - 4) << 6, n0, As, Ws);
}

template <int MODE>
__global__ __launch_bounds__(256, 2) void gemm_kernel(
    const void* __restrict__ Av, const void* __restrict__ A2v,
    const float* __restrict__ W, const void* __restrict__ ADDv,
    void* __restrict__ C0v, int K, int N)
{
    __shared__ __align__(16) double As[2][16][68];
    __shared__ __align__(16) float  Ws[2][16][72];
    gemm_body<MODE>(Av, A2v, W, ADDv, C0v, K, N,
                    blockIdx.y << 6, blockIdx.x << 6, As, Ws);
}

// ----------------------------- Attention core ------------------------------
// One block per token. Patterns pre-packed (pos lo16 | neg hi16).
// S8[t][h][j8] integer-exact; xa = 0.5*S8.V8 (exact in fp32); out f64 /10.
__global__ __launch_bounds__(256) void attn_kernel(
    const unsigned* __restrict__ patq_g, const unsigned* __restrict__ patk_g,
    const unsigned* __restrict__ patv_g, double* __restrict__ Aout)
{
    __shared__ __align__(16) unsigned patq[4096];
    __shared__ __align__(16) unsigned patk[1024];
    __shared__ __align__(16) unsigned patv[1024];
    __shared__ int S8[10][32][8];
    const int n = blockIdx.x, tid = threadIdx.x;

    const uint4* q4 = (const uint4*)(patq_g + (size_t)n * 4096);
#pragma unroll
    for (int r = 0; r < 4; ++r)
        ((uint4*)patq)[tid + (r << 8)] = q4[tid + (r << 8)];
    ((uint4*)patk)[tid] = ((const uint4*)(patk_g + (size_t)n * 1024))[tid];
    ((uint4*)patv)[tid] = ((const uint4*)(patv_g + (size_t)n * 1024))[tid];
    __syncthreads();

    const int hi = tid >> 3;  // head 0..31
    const int j8 = tid & 7;   // kv-head (phase 1) / d-group (phase 2)

    int sacc[10] = {0, 0, 0, 0, 0, 0, 0, 0, 0, 0};
    for (int d = 0; d < 128; ++d) {
        unsigned q = patq[(hi << 7) + d];
        unsigned k = patk[(j8 << 7) + d];
        unsigned qp = q & 0xFFFFu, qn = q >> 16;
        unsigned kp = k & 0xFFFFu, kn = k >> 16;
        unsigned pos = (qp & kp) | (qn & kn);
        unsigned neg = (qp & kn) | (qn & kp);
#pragma unroll
        for (int t = 0; t < 10; ++t)
            sacc[t] += (int)((pos >> t) & 1u) - (int)((neg >> t) & 1u);
    }
#pragma unroll
    for (int t = 0; t < 10; ++t) S8[t][hi][j8] = sacc[t];
    __syncthreads();

    float xacc[16];
#pragma unroll
    for (int dd = 0; dd < 16; ++dd) xacc[dd] = 0.f;

    for (int t = 0; t < 10; ++t) {
        int s8r[8];
#pragma unroll
        for (int jj = 0; jj < 8; ++jj) s8r[jj] = S8[t][hi][jj];
#pragma unroll
        for (int dd = 0; dd < 16; ++dd) {
            int d = (j8 << 4) + dd;
            int acc = 0;
#pragma unroll
            for (int jj = 0; jj < 8; ++jj) {
                unsigned v = patv[(jj << 7) + d];
                int vv = (int)((v >> t) & 1u) - (int)((v >> (t + 16)) & 1u);
                acc += s8r[jj] * vv;
            }
            xacc[dd] += 0.5f * (float)acc;
        }
    }
#pragma unroll
    for (int dd = 0; dd < 16; ++dd) {
        int d = (j8 << 4) + dd;
        Aout[(size_t)n * 4096 + (d << 5) + hi] = (double)xacc[dd] / 10.0;
    }
}

// ----------------------------- Launch --------------------------------------
extern "C" void kernel_launch(void* const* d_in, const int* in_sizes, int n_in,
                              void* d_out, int out_size, void* d_ws, size_t ws_size,
                              hipStream_t stream)
{
    const float* x   = (const float*)d_in[0];
    const float* anw = (const float*)d_in[2];
    const float* fnw = (const float*)d_in[3];
    const float* wq  = (const float*)d_in[4];
    const float* wk  = (const float*)d_in[5];
    const float* wv  = (const float*)d_in[6];
    const float* wo  = (const float*)d_in[7];
    const float* w1  = (const float*)d_in[8];
    const float* w2  = (const float*)d_in[9];
    const float* w3  = (const float*)d_in[10];
    float* out = (float*)d_out;

    double* h1 = (double*)d_ws;            // 256x4096 f64
    double* Ap = h1 + 1048576;             // 256x4096 f64 (pooled attn, c=d*32+h)
    double* hb = Ap + 1048576;             // 256x4096 f64 residual h
    double* h2 = hb + 1048576;             // 256x4096 f64
    unsigned* patq = (unsigned*)(h2 + 1048576);  // 256x4096 u32
    unsigned* patk = patq + 1048576;             // 256x1024 u32
    unsigned* patv = patk + 262144;              // 256x1024 u32
    unsigned char* s1 = (unsigned char*)(patv + 262144);  // 256x14336 u8
    signed char*  s3 = (signed char*)(s1 + 3670016);      // 256x14336 i8
    // total ~45 MB of d_ws

    dim3 blk(256);
    rms_f_kernel<<<dim3(256), blk, 0, stream>>>(x, anw, h1);
    gemm_qkv_kernel<<<dim3(96, 4), blk, 0, stream>>>(h1, wq, wk, wv, patq, patk, patv);
    attn_kernel<<<dim3(256), blk, 0, stream>>>(patq, patk, patv, Ap);
    gemm_kernel<3><<<dim3(64, 4), blk, 0, stream>>>(Ap, nullptr, wo, x, hb, 4096, 4096);
    rms_d_kernel<<<dim3(256), blk, 0, stream>>>(hb, fnw, h2);
    gemm_ffn13_kernel<<<dim3(224, 8), blk, 0, stream>>>(h2, w3, w1, s3, s1);
    gemm_kernel<4><<<dim3(64, 4), blk, 0, stream>>>(s1, s3, w2, hb, out, 14336, 4096);
}